// Round 2
// baseline (318.369 us; speedup 1.0000x reference)
//
#include <hip/hip_runtime.h>
#include <math.h>

typedef _Float16 f16;
typedef _Float16 f16x2 __attribute__((ext_vector_type(2)));
typedef _Float16 f16x8 __attribute__((ext_vector_type(8)));
typedef float    f32x4 __attribute__((ext_vector_type(4)));
typedef float    f32x16 __attribute__((ext_vector_type(16)));

#define NB 4096
#define LT 512
#define NC 16
#define NS 32

// workspace layout (bytes)
#define WS_P0     0                     // 32 f32, softmax(init)*256
#define WS_SIG    128                   // 32 f32, sigmoid(acc)*256
#define WS_SUMSIG 256                   // 1 f32
#define WS_FWDT   512                   // 16384 f16 = 32768 B
#define WS_BWDT   (512 + 32768)
#define WS_F      (512 + 65536)         // 32*4096 f32
#define WS_G      (WS_F + 32*4096*4)

#if __has_builtin(__builtin_amdgcn_exp2f)
#define EXP2F __builtin_amdgcn_exp2f
#else
#define EXP2F exp2f
#endif

// ---------------- prep: softmaxes + fragment-ordered fp16 transition tables ----
__global__ __launch_bounds__(512) void pdfa_prep(const float* __restrict__ tlogit,
                                                 const float* __restrict__ ilogit,
                                                 const float* __restrict__ alogit,
                                                 char* __restrict__ ws) {
    int tid = threadIdx.x;           // 512 threads = one (p,c) row each
    f16* fwdT = (f16*)(ws + WS_FWDT);
    f16* bwdT = (f16*)(ws + WS_BWDT);
    int p = tid >> 4, c = tid & 15;
    const float* row = tlogit + p * 512 + c * 32;
    float mx = row[0];
    for (int n = 1; n < 32; ++n) mx = fmaxf(mx, row[n]);
    float s = 0.f;
    for (int n = 0; n < 32; ++n) s += expf(row[n] - mx);
    float inv = 1.f / s;
    int g = p >> 3, ht = (p >> 2) & 1, d = p & 3;
    int chalf = c >> 3, j = c & 7;
    for (int n = 0; n < 32; ++n) {
        float tv = expf(row[n] - mx) * inv;
        // fwd table: GEMM D[m=n']=sum_k T[p,c,n']*y[k], A row m = lane&31 = n
        {
            int ks = 8 * g + 2 * d + chalf;
            int l = 32 * ht + n;
            fwdT[ks * 512 + l * 8 + j] = (f16)tv;
        }
        // bwd table: D[m=p]=sum_{(c,n)} T[p,c,n]*x[c]g[n], A row m = p
        {
            int g2 = n >> 3, h2 = (n >> 2) & 1, d2 = n & 3;
            int ks = 8 * g2 + 2 * d2 + chalf;
            int l = 32 * h2 + p;
            bwdT[ks * 512 + l * 8 + j] = (f16)tv;
        }
    }
    if (tid < 32) {
        float m0 = ilogit[0];
        for (int n = 1; n < 32; ++n) m0 = fmaxf(m0, ilogit[n]);
        float s0 = 0.f;
        for (int n = 0; n < 32; ++n) s0 += expf(ilogit[n] - m0);
        ((float*)(ws + WS_P0))[tid]  = 256.f * expf(ilogit[tid] - m0) / s0;
        ((float*)(ws + WS_SIG))[tid] = 256.f / (1.f + expf(-alogit[tid]));
    }
    if (tid == 0) {
        float ss = 0.f;
        for (int n = 0; n < 32; ++n) ss += 1.f / (1.f + expf(-alogit[n]));
        *(float*)(ws + WS_SUMSIG) = ss;
    }
}

// ---------------- main: 256 independent wave-chains (128 seq-tiles x fwd/bwd) --
#define EC(v) ((f16)EXP2F((v) * 1.44269504089f))

#define XLOAD(B0,B1,B2,B3,T) { const f32x4* sp_ = (const f32x4*)(xbase + (size_t)(T) * NC); \
    B0 = sp_[0]; B1 = sp_[1]; B2 = sp_[2]; B3 = sp_[3]; }

#define XCONV(B0,B1,B2,B3) { \
    xq[0] = f16x2{EC(B0[0]), EC(B0[1])}; \
    xq[1] = f16x2{EC(B0[2]), EC(B0[3])}; \
    xq[2] = f16x2{EC(B1[0]), EC(B1[1])}; \
    xq[3] = f16x2{EC(B1[2]), EC(B1[3])}; \
    xq[4] = f16x2{EC(B2[0]), EC(B2[1])}; \
    xq[5] = f16x2{EC(B2[2]), EC(B2[3])}; \
    xq[6] = f16x2{EC(B3[0]), EC(B3[1])}; \
    xq[7] = f16x2{EC(B3[2]), EC(B3[3])}; }

// one K-step: pre-broadcast state pair, 4x v_pk_mul_f16, one MFMA into chain (KS&7)
// pidx = local-state index for this k-slice; ch = which 8 x-values (c-half)
#define KSTEP8(KS, CIN) { \
    enum { ks_ = (KS), pidx_ = 4*((KS)>>3) + 2*(((KS)>>2)&1) + (((KS)>>1)&1), ch_ = ((KS)&1)*4 }; \
    f16x2 y0_ = ppb[pidx_] * xq[ch_+0], y1_ = ppb[pidx_] * xq[ch_+1]; \
    f16x2 y2_ = ppb[pidx_] * xq[ch_+2], y3_ = ppb[pidx_] * xq[ch_+3]; \
    f16x8 bf_ = {y0_[0],y0_[1],y1_[0],y1_[1],y2_[0],y2_[1],y3_[0],y3_[1]}; \
    acc[(KS)&7] = __builtin_amdgcn_mfma_f32_32x32x16_f16(af[ks_], bf_, CIN, 0, 0, 0); }

// 8 independent accumulator chains of depth 4 (dep distance = 8 MFMA issues),
// then 3-level tree reduce + rebuild broadcast state regs for the next step.
#define STEPBODY() { \
    f32x16 acc[8]; \
    KSTEP8(0,  z)      KSTEP8(1,  z)      KSTEP8(2,  z)      KSTEP8(3,  z) \
    KSTEP8(4,  z)      KSTEP8(5,  z)      KSTEP8(6,  z)      KSTEP8(7,  z) \
    KSTEP8(8,  acc[0]) KSTEP8(9,  acc[1]) KSTEP8(10, acc[2]) KSTEP8(11, acc[3]) \
    KSTEP8(12, acc[4]) KSTEP8(13, acc[5]) KSTEP8(14, acc[6]) KSTEP8(15, acc[7]) \
    KSTEP8(16, acc[0]) KSTEP8(17, acc[1]) KSTEP8(18, acc[2]) KSTEP8(19, acc[3]) \
    KSTEP8(20, acc[4]) KSTEP8(21, acc[5]) KSTEP8(22, acc[6]) KSTEP8(23, acc[7]) \
    KSTEP8(24, acc[0]) KSTEP8(25, acc[1]) KSTEP8(26, acc[2]) KSTEP8(27, acc[3]) \
    KSTEP8(28, acc[4]) KSTEP8(29, acc[5]) KSTEP8(30, acc[6]) KSTEP8(31, acc[7]) \
    f32x16 s01_ = acc[0] + acc[1], s23_ = acc[2] + acc[3]; \
    f32x16 s45_ = acc[4] + acc[5], s67_ = acc[6] + acc[7]; \
    f32x16 t0_ = s01_ + s23_, t1_ = s45_ + s67_; \
    pfin = t0_ + t1_; \
    _Pragma("unroll") \
    for (int j_ = 0; j_ < 16; ++j_) { f16 v_ = (f16)pfin[j_]; ppb[j_] = f16x2{v_, v_}; } }

__global__ __launch_bounds__(64, 1) void pdfa_main(const float* __restrict__ login,
                                                   char* __restrict__ ws) {
    const int lane = threadIdx.x;
    const int br = lane & 31, hi = lane >> 5;
    const int bid = blockIdx.x;
    const int dir = bid & 1;               // 0 = forward (t 0..255), 1 = backward (t 511..256)
    const int b0 = (bid >> 1) << 5;

    // constant A-operand fragments (transition table), 32 frags x 16B = 128 VGPRs
    const char* tblb = ws + (dir ? WS_BWDT : WS_FWDT);
    f16x8 af[32];
#pragma unroll
    for (int ks = 0; ks < 32; ++ks)
        af[ks] = *(const f16x8*)(tblb + ks * 1024 + lane * 16);

    // init state: 16 local states, each pre-broadcast into both halves of an f16x2
    const float* initv = (const float*)(ws + (dir ? WS_SIG : WS_P0));
    f16x2 ppb[16];
#pragma unroll
    for (int j = 0; j < 16; ++j) {
        int st = 8 * (j >> 2) + 4 * hi + 2 * ((j >> 1) & 1) + (j & 1);
        f16 v = (f16)initv[st];
        ppb[j] = f16x2{v, v};
    }

    const float* xbase = login + (size_t)(b0 + br) * (LT * NC);
    const f32x16 z{};
    f32x16 pfin{};
    f16x2 xq[8];
    f32x4 xa0, xa1, xa2, xa3, xb0, xb1, xb2, xb3;

#define TT(S) (dir ? (511 - (S)) : (S))
    XLOAD(xa0, xa1, xa2, xa3, TT(0))
    XLOAD(xb0, xb1, xb2, xb3, TT(1))

    for (int s = 0; s < 256; s += 2) {
        XCONV(xa0, xa1, xa2, xa3)
        XLOAD(xa0, xa1, xa2, xa3, TT(s + 2))   // depth-2 prefetch (t<=257 / >=254: in range)
        STEPBODY()
        XCONV(xb0, xb1, xb2, xb3)
        XLOAD(xb0, xb1, xb2, xb3, TT(s + 3))
        STEPBODY()
    }
#undef TT

    // write fp32 result vector: f (fwd) or g (bwd), laid out [state][b]
    float* outv = (float*)(ws + (dir ? WS_G : WS_F));
#pragma unroll
    for (int r = 0; r < 16; ++r) {
        int st = (r & 3) + 8 * (r >> 2) + 4 * hi;
        outv[st * NB + b0 + br] = pfin[r];
    }
}

// ---------------- combine: out[b] = log( f.g / 65536 + 1e-20*sum(sigma) ) ------
__global__ __launch_bounds__(256) void pdfa_combine(const char* __restrict__ ws,
                                                    float* __restrict__ out) {
    int b = blockIdx.x * 256 + threadIdx.x;
    const float* f = (const float*)(ws + WS_F);
    const float* g = (const float*)(ws + WS_G);
    float ss = *(const float*)(ws + WS_SUMSIG);
    float dot = 0.f;
#pragma unroll
    for (int s2 = 0; s2 < 32; ++s2)
        dot = fmaf(f[s2 * NB + b], g[s2 * NB + b], dot);
    out[b] = logf(dot * (1.f / 65536.f) + 1e-20f * ss);
}

extern "C" void kernel_launch(void* const* d_in, const int* in_sizes, int n_in,
                              void* d_out, int out_size, void* d_ws, size_t ws_size,
                              hipStream_t stream) {
    const float* login = (const float*)d_in[0];
    const float* ilog  = (const float*)d_in[1];
    const float* tlog  = (const float*)d_in[2];
    const float* alog  = (const float*)d_in[3];
    char* ws = (char*)d_ws;

    pdfa_prep<<<1, 512, 0, stream>>>(tlog, ilog, alog, ws);
    pdfa_main<<<256, 64, 0, stream>>>(login, ws);
    pdfa_combine<<<NB / 256, 256, 0, stream>>>(ws, (float*)d_out);
}